// Round 7
// baseline (269.830 us; speedup 1.0000x reference)
//
#include <hip/hip_runtime.h>

typedef unsigned short u16;
typedef unsigned int u32;
typedef __attribute__((ext_vector_type(4))) float f32x4;
typedef __attribute__((ext_vector_type(8))) __bf16 bf16x8;
typedef __attribute__((ext_vector_type(4))) u16 u16x4;
typedef const __attribute__((address_space(1))) void* as1cv;
typedef __attribute__((address_space(3))) void* as3v;

static __device__ __forceinline__ float bf2f(u16 v) {
  union { u32 u; float f; } x; x.u = ((u32)v) << 16; return x.f;
}
static __device__ __forceinline__ u16 f2bf(float f) {
  union { float f; u32 u; } x; x.f = f;
  u32 r = x.u + 0x7FFFu + ((x.u >> 16) & 1u);
  return (u16)(r >> 16);
}

// ---------------- prep kernels ----------------

// x (B,E,T) f32 -> xtp (B, T+2, E) bf16, xtp[b][t+1][e] = x[b][e][t]; pad rows in k_prep
__global__ void __launch_bounds__(256) k_transpose(const float* __restrict__ x,
                                                   u16* __restrict__ xtp) {
  __shared__ float tile[32][33];
  const int b = blockIdx.z;
  const int t0 = blockIdx.x * 32, e0 = blockIdx.y * 32;
  const int tx = threadIdx.x & 31, ty = threadIdx.x >> 5;
  const float* src = x + (size_t)b * 512 * 512;
#pragma unroll
  for (int i = 0; i < 32; i += 8)
    tile[ty + i][tx] = src[(size_t)(e0 + ty + i) * 512 + t0 + tx];
  __syncthreads();
  u16* dst = xtp + (size_t)b * 514 * 512;
#pragma unroll
  for (int i = 0; i < 32; i += 8)
    dst[(size_t)(t0 + ty + i + 1) * 512 + e0 + tx] = f2bf(tile[tx][ty + i]);
}

// fused prep: conv-weight pack (idx<524288), MLP weight cvt (i<401408),
// logits zero + pad rows + passthrough (i<262144). grid 2048x256.
__global__ void __launch_bounds__(256) k_prep(
    const float* __restrict__ wa, const float* __restrict__ wb,
    u16* __restrict__ ga, u16* __restrict__ gb,
    const float* __restrict__ w1, const float* __restrict__ w2,
    const float* __restrict__ wr, u16* __restrict__ wdst,
    u16* __restrict__ xtp0, u16* __restrict__ xtp1,
    const float* __restrict__ trig, const int* __restrict__ labels,
    float* __restrict__ out) {
  const int idx = blockIdx.x * 256 + threadIdx.x;  // < 524288
  {  // conv weights (E,E,W) f32 -> Wg (E, 3*E) bf16, Wg[o][w*512+i] = w[o][i][w]
    const float* w = (idx < 262144) ? wa : wb;
    u16* g = (idx < 262144) ? ga : gb;
    const int id = idx & 262143;
    const int o = id >> 9, i = id & 511;
    const float* p = w + (size_t)id * 3;
    g[(size_t)o * 1536 + i]        = f2bf(p[0]);
    g[(size_t)o * 1536 + 512 + i]  = f2bf(p[1]);
    g[(size_t)o * 1536 + 1024 + i] = f2bf(p[2]);
  }
  if (idx < 401408) {  // w1|w2|wr f32 -> contiguous bf16, x4 elems
    const int e0 = idx * 4;
    const float* src; int off;
    if (e0 < 524288)       { src = w1; off = e0; }
    else if (e0 < 1572864) { src = w2; off = e0 - 524288; }
    else                   { src = wr; off = e0 - 1572864; }
    const float4 v = *(const float4*)(src + off);
    u16x4 r; r.x = f2bf(v.x); r.y = f2bf(v.y); r.z = f2bf(v.z); r.w = f2bf(v.w);
    *(u16x4*)(wdst + e0) = r;
  }
  if (idx < 262144) out[idx] = 0.f;  // logits zero-init (split-K atomics)
  if (idx < 16384) {                 // zero pad rows of xtp0/xtp1
    const int b = idx >> 10, rem = idx & 1023;
    const int row = (rem >> 9) ? 513 : 0, e = rem & 511;
    const size_t off = (size_t)b * 514 * 512 + (size_t)row * 512 + e;
    xtp0[off] = 0;
    xtp1[off] = 0;
  }
  if (idx < 8192) {
    out[262144 + idx] = trig[idx];           // trig_attn passthrough (B*T)
    out[270336 + idx] = (float)labels[idx];  // rel_labels passthrough (P)
  }
}

// ---------------- span max ----------------
__global__ void __launch_bounds__(256) k_spanmax(const u16* __restrict__ xt2,
    const int* __restrict__ bidx, const int* __restrict__ hidx, const int* __restrict__ hspan,
    const int* __restrict__ tidx, const int* __restrict__ tspan, u16* __restrict__ maxed) {
  const int p = blockIdx.x;
  const int b = bidx[p], h0 = hidx[p], hn = hspan[p], t0 = tidx[p], tn = tspan[p];
  const u32* base = (const u32*)(xt2 + (size_t)b * 512 * 512);
  const int e = threadIdx.x;  // covers bf16 pair (2e, 2e+1)
  float m0 = -1e30f, m1 = -1e30f, q0 = -1e30f, q1 = -1e30f;
  for (int s = 0; s < hn; ++s) {
    const u32 v = base[(size_t)(h0 + s) * 256 + e];
    m0 = fmaxf(m0, bf2f((u16)v));
    m1 = fmaxf(m1, bf2f((u16)(v >> 16)));
  }
  for (int s = 0; s < tn; ++s) {
    const u32 v = base[(size_t)(t0 + s) * 256 + e];
    q0 = fmaxf(q0, bf2f((u16)v));
    q1 = fmaxf(q1, bf2f((u16)(v >> 16)));
  }
  const u32 r = (u32)f2bf(m0 + q0) | ((u32)f2bf(m1 + q1) << 16);
  ((u32*)(maxed + (size_t)p * 512))[e] = r;
}

// ---------------- GEMM (m97-style 2-phase, global_load_lds, 16x16x32 bf16 MFMA) ----------------
// C[m][n] = sum_k A[m][k]*Bw[n][k]; epilogue: +bias[n], optional relu, optional +resid,
// store bf16/f32, optional atomicAdd (split-K; bias applied by z==0 only).
// CONV: A row gets +(k0>>9) shift, col = k0&511 (K = 3*512 im2col over padded xT).
template<int BM, int BN, int WM, int WN, int CONV, int RELU, int RESID, int OUTF32, int ATOMIC>
__global__ void __launch_bounds__(256, 2) k_gemm(
    const u16* __restrict__ A, int strideA, long long batchA,
    const u16* __restrict__ Bw, int strideB, long long batchB, int K,
    const float* __restrict__ bias,
    const u16* __restrict__ resid, long long batchR,
    void* __restrict__ outp, long long batchO, int strideO) {
  constexpr int FM = BM / (16 * WM);
  constexpr int FN = BN / (16 * WN);
  constexpr int CA = BM / 16, CB = BN / 16;
  __shared__ __align__(16) u16 lds[2][(BM + BN) * 32];
  const int tid = threadIdx.x;
  const int wave = tid >> 6, lane = tid & 63;
  const int z = blockIdx.z;
  const int m0 = blockIdx.y * BM, n0 = blockIdx.x * BN;
  const u16* Ab = A + (size_t)z * batchA;
  const u16* Bb = Bw + (size_t)z * batchB;
  const int NT = K >> 5;

  auto stage = [&](int t, int buf) {
    const int k0 = t << 5;
    const int arow = CONV ? (k0 >> 9) : 0;
    const int acol = CONV ? (k0 & 511) : k0;
    for (int c = wave; c < CA + CB; c += 4) {
      const u16* gsrc;
      u16* ldst;
      if (c < CA) {
        const int r0 = c << 4;
        ldst = &lds[buf][r0 * 32];
        const int row = m0 + r0 + (lane >> 2) + arow;
        gsrc = Ab + (size_t)row * strideA + acol + ((lane & 3) << 3);
      } else {
        const int r0 = (c - CA) << 4;
        ldst = &lds[buf][BM * 32 + r0 * 32];
        const int row = n0 + r0 + (lane >> 2);
        gsrc = Bb + (size_t)row * strideB + k0 + ((lane & 3) << 3);
      }
      __builtin_amdgcn_global_load_lds((as1cv)gsrc, (as3v)ldst, 16, 0, 0);
    }
  };

  f32x4 acc[FM][FN];
  const f32x4 zero4 = {0.f, 0.f, 0.f, 0.f};
#pragma unroll
  for (int m = 0; m < FM; ++m)
#pragma unroll
    for (int n = 0; n < FN; ++n) acc[m][n] = zero4;

  const int wrow = wave / WN, wcol = wave % WN;
  const int rsel = lane & 15;
  const int kc = (lane >> 4) << 3;

  stage(0, 0);
  __syncthreads();
  int cur = 0;
  for (int t = 0; t < NT; ++t) {
    if (t + 1 < NT) stage(t + 1, cur ^ 1);
    const u16* As = lds[cur];
    const u16* Bs = lds[cur] + BM * 32;
    bf16x8 af[FM], bq[FN];
#pragma unroll
    for (int m = 0; m < FM; ++m)
      af[m] = *(const bf16x8*)&As[(wrow * FM * 16 + m * 16 + rsel) * 32 + kc];
#pragma unroll
    for (int n = 0; n < FN; ++n)
      bq[n] = *(const bf16x8*)&Bs[(wcol * FN * 16 + n * 16 + rsel) * 32 + kc];
#pragma unroll
    for (int m = 0; m < FM; ++m)
#pragma unroll
      for (int n = 0; n < FN; ++n)
        acc[m][n] = __builtin_amdgcn_mfma_f32_16x16x32_bf16(af[m], bq[n], acc[m][n], 0, 0, 0);
    __syncthreads();
    cur ^= 1;
  }

  // epilogue: C/D layout col = lane&15, row = (lane>>4)*4 + reg  [verified m89/m91]
  const int rowbase = m0 + wrow * FM * 16 + ((lane >> 4) << 2);
  const int colbase = n0 + wcol * FN * 16 + rsel;
  float bv[FN];
#pragma unroll
  for (int n = 0; n < FN; ++n)
    bv[n] = (!ATOMIC || z == 0) ? bias[colbase + n * 16] : 0.f;
  const u16* Rb = RESID ? (resid + (size_t)z * batchR) : (const u16*)nullptr;
  float* of = (float*)outp;
  u16* ob = (u16*)outp;
  const size_t obase = (size_t)z * batchO;
#pragma unroll
  for (int m = 0; m < FM; ++m) {
#pragma unroll
    for (int r = 0; r < 4; ++r) {
      const int row = rowbase + m * 16 + r;
#pragma unroll
      for (int n = 0; n < FN; ++n) {
        const int col = colbase + n * 16;
        float v = acc[m][n][r] + bv[n];
        if (RELU) v = fmaxf(v, 0.f);
        if (RESID) v += bf2f(Rb[(size_t)row * strideO + col]);
        const size_t o = obase + (size_t)row * strideO + col;
        if (ATOMIC) atomicAdd(&of[o], v);
        else if (OUTF32) of[o] = v;
        else ob[o] = f2bf(v);
      }
    }
  }
}

// ---------------- launcher ----------------
extern "C" void kernel_launch(void* const* d_in, const int* in_sizes, int n_in,
                              void* d_out, int out_size, void* d_ws, size_t ws_size,
                              hipStream_t stream) {
  const float* x    = (const float*)d_in[0];
  const float* trig = (const float*)d_in[1];
  const int* bidx   = (const int*)d_in[2];
  const int* hidx   = (const int*)d_in[3];
  const int* hspan  = (const int*)d_in[4];
  const int* tidx   = (const int*)d_in[5];
  const int* tspan  = (const int*)d_in[6];
  const int* labels = (const int*)d_in[7];
  const float* c1w  = (const float*)d_in[8];
  const float* c1b  = (const float*)d_in[9];
  const float* c2w  = (const float*)d_in[10];
  const float* c2b  = (const float*)d_in[11];
  const float* w1   = (const float*)d_in[12];
  const float* b1   = (const float*)d_in[13];
  const float* w2   = (const float*)d_in[14];
  const float* b2   = (const float*)d_in[15];
  const float* wrp  = (const float*)d_in[16];
  const float* br   = (const float*)d_in[17];
  float* out = (float*)d_out;
  char* ws = (char*)d_ws;
  (void)in_sizes; (void)n_in; (void)out_size; (void)ws_size;

  const size_t S_xtp = (size_t)16 * 514 * 512 * 2;  // 8,421,376 B padded transposed activations
  u16* xtp0  = (u16*)(ws);
  u16* xtp1  = (u16*)(ws + S_xtp);
  u16* xt2   = (u16*)(ws);            // overlays xtp0 (dead after conv1)
  u16* maxed = (u16*)(ws + S_xtp);    // overlays xtp1 (dead after conv2)
  u16* h2    = (u16*)(ws);            // overlays xt2+maxed (dead after gemm1)
  u16* h1    = (u16*)(ws + 2 * S_xtp);                            // 16 MiB
  u16* wg1   = (u16*)(ws + 2 * S_xtp + (size_t)16 * 1024 * 1024);
  u16* wg2   = wg1 + (size_t)512 * 1536;
  u16* w1b   = wg2 + (size_t)512 * 1536;
  u16* w2b   = w1b + (size_t)1024 * 512;
  u16* wrb   = w2b + (size_t)1024 * 1024;   // total ws use ~38.1 MiB

  k_transpose<<<dim3(16, 16, 16), 256, 0, stream>>>(x, xtp0);
  k_prep<<<2048, 256, 0, stream>>>(c1w, c2w, wg1, wg2, w1, w2, wrp, w1b,
                                   xtp0, xtp1, trig, labels, out);

  // conv1: y[b][t][o] = relu(sum_k xT0[b][t+w][i]*Wg1[o][k]) + xT0[b][t+1][o]
  // 128x64 tile: FM=4,FN=2 -> 8 MFMA : 6 ds_read (was 64^2 = 4:4, LDS-read-bound);
  // grid 512 = 2 blocks/CU co-resident, LDS 24 KB.
  k_gemm<128, 64, 2, 2, 1, 1, 1, 0, 0><<<dim3(8, 4, 16), 256, 0, stream>>>(
      xtp0, 512, (long long)514 * 512, wg1, 1536, 0, 1536, c1b,
      xtp0 + 512, (long long)514 * 512,
      xtp1 + 512, (long long)514 * 512, 512);
  // conv2 -> xt2 (B,T,E), unpadded
  k_gemm<128, 64, 2, 2, 1, 1, 1, 0, 0><<<dim3(8, 4, 16), 256, 0, stream>>>(
      xtp1, 512, (long long)514 * 512, wg2, 1536, 0, 1536, c2b,
      xtp1 + 512, (long long)514 * 512,
      xt2, (long long)512 * 512, 512);

  k_spanmax<<<8192, 256, 0, stream>>>(xt2, bidx, hidx, hspan, tidx, tspan, maxed);

  // h1 = relu(maxed @ w1^T + b1)   (8192x1024, K=512) — 128x64 tiles, 1024 blocks (4/CU, density 8:6)
  k_gemm<128, 64, 2, 2, 0, 1, 0, 0, 0><<<dim3(16, 64, 1), 256, 0, stream>>>(
      maxed, 512, 0, w1b, 512, 0, 512, b1, nullptr, 0, h1, 0, 1024);
  // h2 = relu(h1 @ w2^T + b2)      (8192x1024, K=1024) — 128x128 tiles, 512 blocks (2/CU, density 16:8)
  // A/B vs gemm1's structure: next round's per-FLOP time decides the final tile for both.
  k_gemm<128, 128, 2, 2, 0, 1, 0, 0, 0><<<dim3(8, 64, 1), 256, 0, stream>>>(
      h1, 1024, 0, w2b, 1024, 0, 1024, b2, nullptr, 0, h2, 0, 1024);
  // logits = h2 @ wr^T + br -> d_out[0 : 8192*32] f32; split-K x4 with atomic adds
  k_gemm<64, 32, 2, 2, 0, 0, 0, 1, 1><<<dim3(1, 128, 4), 256, 0, stream>>>(
      h2, 1024, 256, wrb, 1024, 256, 256, br, nullptr, 0, out, 0, 32);
}

// Round 8
// 247.168 us; speedup vs baseline: 1.0917x; 1.0917x over previous
//
#include <hip/hip_runtime.h>

typedef unsigned short u16;
typedef unsigned int u32;
typedef __attribute__((ext_vector_type(4))) float f32x4;
typedef __attribute__((ext_vector_type(8))) __bf16 bf16x8;
typedef __attribute__((ext_vector_type(4))) u16 u16x4;
typedef const __attribute__((address_space(1))) void* as1cv;
typedef __attribute__((address_space(3))) void* as3v;

static __device__ __forceinline__ float bf2f(u16 v) {
  union { u32 u; float f; } x; x.u = ((u32)v) << 16; return x.f;
}
static __device__ __forceinline__ u16 f2bf(float f) {
  union { float f; u32 u; } x; x.f = f;
  u32 r = x.u + 0x7FFFu + ((x.u >> 16) & 1u);
  return (u16)(r >> 16);
}

// ---------------- prep kernels ----------------

// x (B,E,T) f32 -> xtp (B, T+2, E) bf16, xtp[b][t+1][e] = x[b][e][t]; pad rows in k_prep
__global__ void __launch_bounds__(256) k_transpose(const float* __restrict__ x,
                                                   u16* __restrict__ xtp) {
  __shared__ float tile[32][33];
  const int b = blockIdx.z;
  const int t0 = blockIdx.x * 32, e0 = blockIdx.y * 32;
  const int tx = threadIdx.x & 31, ty = threadIdx.x >> 5;
  const float* src = x + (size_t)b * 512 * 512;
#pragma unroll
  for (int i = 0; i < 32; i += 8)
    tile[ty + i][tx] = src[(size_t)(e0 + ty + i) * 512 + t0 + tx];
  __syncthreads();
  u16* dst = xtp + (size_t)b * 514 * 512;
#pragma unroll
  for (int i = 0; i < 32; i += 8)
    dst[(size_t)(t0 + ty + i + 1) * 512 + e0 + tx] = f2bf(tile[tx][ty + i]);
}

// fused prep: conv-weight pack (idx<524288), MLP weight cvt (i<401408),
// logits zero + pad rows + passthrough (i<262144). grid 2048x256.
__global__ void __launch_bounds__(256) k_prep(
    const float* __restrict__ wa, const float* __restrict__ wb,
    u16* __restrict__ ga, u16* __restrict__ gb,
    const float* __restrict__ w1, const float* __restrict__ w2,
    const float* __restrict__ wr, u16* __restrict__ wdst,
    u16* __restrict__ xtp0, u16* __restrict__ xtp1,
    const float* __restrict__ trig, const int* __restrict__ labels,
    float* __restrict__ out) {
  const int idx = blockIdx.x * 256 + threadIdx.x;  // < 524288
  {  // conv weights (E,E,W) f32 -> Wg (E, 3*E) bf16, Wg[o][w*512+i] = w[o][i][w]
    const float* w = (idx < 262144) ? wa : wb;
    u16* g = (idx < 262144) ? ga : gb;
    const int id = idx & 262143;
    const int o = id >> 9, i = id & 511;
    const float* p = w + (size_t)id * 3;
    g[(size_t)o * 1536 + i]        = f2bf(p[0]);
    g[(size_t)o * 1536 + 512 + i]  = f2bf(p[1]);
    g[(size_t)o * 1536 + 1024 + i] = f2bf(p[2]);
  }
  if (idx < 401408) {  // w1|w2|wr f32 -> contiguous bf16, x4 elems
    const int e0 = idx * 4;
    const float* src; int off;
    if (e0 < 524288)       { src = w1; off = e0; }
    else if (e0 < 1572864) { src = w2; off = e0 - 524288; }
    else                   { src = wr; off = e0 - 1572864; }
    const float4 v = *(const float4*)(src + off);
    u16x4 r; r.x = f2bf(v.x); r.y = f2bf(v.y); r.z = f2bf(v.z); r.w = f2bf(v.w);
    *(u16x4*)(wdst + e0) = r;
  }
  if (idx < 262144) out[idx] = 0.f;  // logits zero-init (split-K atomics)
  if (idx < 16384) {                 // zero pad rows of xtp0/xtp1
    const int b = idx >> 10, rem = idx & 1023;
    const int row = (rem >> 9) ? 513 : 0, e = rem & 511;
    const size_t off = (size_t)b * 514 * 512 + (size_t)row * 512 + e;
    xtp0[off] = 0;
    xtp1[off] = 0;
  }
  if (idx < 8192) {
    out[262144 + idx] = trig[idx];           // trig_attn passthrough (B*T)
    out[270336 + idx] = (float)labels[idx];  // rel_labels passthrough (P)
  }
}

// ---------------- span max ----------------
__global__ void __launch_bounds__(256) k_spanmax(const u16* __restrict__ xt2,
    const int* __restrict__ bidx, const int* __restrict__ hidx, const int* __restrict__ hspan,
    const int* __restrict__ tidx, const int* __restrict__ tspan, u16* __restrict__ maxed) {
  const int p = blockIdx.x;
  const int b = bidx[p], h0 = hidx[p], hn = hspan[p], t0 = tidx[p], tn = tspan[p];
  const u32* base = (const u32*)(xt2 + (size_t)b * 512 * 512);
  const int e = threadIdx.x;  // covers bf16 pair (2e, 2e+1)
  float m0 = -1e30f, m1 = -1e30f, q0 = -1e30f, q1 = -1e30f;
  for (int s = 0; s < hn; ++s) {
    const u32 v = base[(size_t)(h0 + s) * 256 + e];
    m0 = fmaxf(m0, bf2f((u16)v));
    m1 = fmaxf(m1, bf2f((u16)(v >> 16)));
  }
  for (int s = 0; s < tn; ++s) {
    const u32 v = base[(size_t)(t0 + s) * 256 + e];
    q0 = fmaxf(q0, bf2f((u16)v));
    q1 = fmaxf(q1, bf2f((u16)(v >> 16)));
  }
  const u32 r = (u32)f2bf(m0 + q0) | ((u32)f2bf(m1 + q1) << 16);
  ((u32*)(maxed + (size_t)p * 512))[e] = r;
}

// ---------------- GEMM (m97-style 2-phase, global_load_lds, 16x16x32 bf16 MFMA) ----------------
// C[m][n] = sum_k A[m][k]*Bw[n][k]; epilogue: +bias[n], optional relu, optional +resid,
// store bf16/f32, optional atomicAdd (split-K; bias applied by z==0 only).
// CONV: A row gets +(k0>>9) shift, col = k0&511 (K = 3*512 im2col over padded xT).
// SWZ: 1-D grid; lin%8 = XCD (HW round-robin) owns whole (y,z)-panels with ALL their
// n-tiles -> A-panel + B resident in that XCD's 4MB L2 (fixes 8x cross-XCD over-fetch,
// measured 101.5MB FETCH/dispatch in r7). swz_nx = n-tiles, swz_nyb = y-tiles,
// swz_pp = panels per XCD. Requires gridSize % 8 == 0 (bijective).
template<int BM, int BN, int WM, int WN, int CONV, int RELU, int RESID, int OUTF32,
         int ATOMIC, int SWZ>
__global__ void __launch_bounds__(256, 2) k_gemm(
    const u16* __restrict__ A, int strideA, long long batchA,
    const u16* __restrict__ Bw, int strideB, long long batchB, int K,
    const float* __restrict__ bias,
    const u16* __restrict__ resid, long long batchR,
    void* __restrict__ outp, long long batchO, int strideO,
    int swz_nx, int swz_nyb, int swz_pp) {
  constexpr int FM = BM / (16 * WM);
  constexpr int FN = BN / (16 * WN);
  constexpr int CA = BM / 16, CB = BN / 16;
  __shared__ __align__(16) u16 lds[2][(BM + BN) * 32];
  const int tid = threadIdx.x;
  const int wave = tid >> 6, lane = tid & 63;
  int m0, n0, z;
  if constexpr (SWZ) {
    const int lin = blockIdx.x;
    const int xcd = lin & 7, slot = lin >> 3;
    const int xb = slot % swz_nx;
    const int p  = xcd * swz_pp + slot / swz_nx;
    m0 = (p % swz_nyb) * BM;
    n0 = xb * BN;
    z  = p / swz_nyb;
  } else {
    m0 = blockIdx.y * BM; n0 = blockIdx.x * BN; z = blockIdx.z;
  }
  const u16* Ab = A + (size_t)z * batchA;
  const u16* Bb = Bw + (size_t)z * batchB;
  const int NT = K >> 5;

  auto stage = [&](int t, int buf) {
    const int k0 = t << 5;
    const int arow = CONV ? (k0 >> 9) : 0;
    const int acol = CONV ? (k0 & 511) : k0;
    for (int c = wave; c < CA + CB; c += 4) {
      const u16* gsrc;
      u16* ldst;
      if (c < CA) {
        const int r0 = c << 4;
        ldst = &lds[buf][r0 * 32];
        const int row = m0 + r0 + (lane >> 2) + arow;
        gsrc = Ab + (size_t)row * strideA + acol + ((lane & 3) << 3);
      } else {
        const int r0 = (c - CA) << 4;
        ldst = &lds[buf][BM * 32 + r0 * 32];
        const int row = n0 + r0 + (lane >> 2);
        gsrc = Bb + (size_t)row * strideB + k0 + ((lane & 3) << 3);
      }
      __builtin_amdgcn_global_load_lds((as1cv)gsrc, (as3v)ldst, 16, 0, 0);
    }
  };

  f32x4 acc[FM][FN];
  const f32x4 zero4 = {0.f, 0.f, 0.f, 0.f};
#pragma unroll
  for (int m = 0; m < FM; ++m)
#pragma unroll
    for (int n = 0; n < FN; ++n) acc[m][n] = zero4;

  const int wrow = wave / WN, wcol = wave % WN;
  const int rsel = lane & 15;
  const int kc = (lane >> 4) << 3;

  stage(0, 0);
  __syncthreads();
  int cur = 0;
  for (int t = 0; t < NT; ++t) {
    if (t + 1 < NT) stage(t + 1, cur ^ 1);
    const u16* As = lds[cur];
    const u16* Bs = lds[cur] + BM * 32;
    bf16x8 af[FM], bq[FN];
#pragma unroll
    for (int m = 0; m < FM; ++m)
      af[m] = *(const bf16x8*)&As[(wrow * FM * 16 + m * 16 + rsel) * 32 + kc];
#pragma unroll
    for (int n = 0; n < FN; ++n)
      bq[n] = *(const bf16x8*)&Bs[(wcol * FN * 16 + n * 16 + rsel) * 32 + kc];
#pragma unroll
    for (int m = 0; m < FM; ++m)
#pragma unroll
      for (int n = 0; n < FN; ++n)
        acc[m][n] = __builtin_amdgcn_mfma_f32_16x16x32_bf16(af[m], bq[n], acc[m][n], 0, 0, 0);
    __syncthreads();
    cur ^= 1;
  }

  // epilogue: C/D layout col = lane&15, row = (lane>>4)*4 + reg  [verified m89/m91]
  const int rowbase = m0 + wrow * FM * 16 + ((lane >> 4) << 2);
  const int colbase = n0 + wcol * FN * 16 + rsel;
  float bv[FN];
#pragma unroll
  for (int n = 0; n < FN; ++n)
    bv[n] = (!ATOMIC || z == 0) ? bias[colbase + n * 16] : 0.f;
  const u16* Rb = RESID ? (resid + (size_t)z * batchR) : (const u16*)nullptr;
  float* of = (float*)outp;
  u16* ob = (u16*)outp;
  const size_t obase = (size_t)z * batchO;
#pragma unroll
  for (int m = 0; m < FM; ++m) {
#pragma unroll
    for (int r = 0; r < 4; ++r) {
      const int row = rowbase + m * 16 + r;
#pragma unroll
      for (int n = 0; n < FN; ++n) {
        const int col = colbase + n * 16;
        float v = acc[m][n][r] + bv[n];
        if (RELU) v = fmaxf(v, 0.f);
        if (RESID) v += bf2f(Rb[(size_t)row * strideO + col]);
        const size_t o = obase + (size_t)row * strideO + col;
        if (ATOMIC) atomicAdd(&of[o], v);
        else if (OUTF32) of[o] = v;
        else ob[o] = f2bf(v);
      }
    }
  }
}

// ---------------- launcher ----------------
extern "C" void kernel_launch(void* const* d_in, const int* in_sizes, int n_in,
                              void* d_out, int out_size, void* d_ws, size_t ws_size,
                              hipStream_t stream) {
  const float* x    = (const float*)d_in[0];
  const float* trig = (const float*)d_in[1];
  const int* bidx   = (const int*)d_in[2];
  const int* hidx   = (const int*)d_in[3];
  const int* hspan  = (const int*)d_in[4];
  const int* tidx   = (const int*)d_in[5];
  const int* tspan  = (const int*)d_in[6];
  const int* labels = (const int*)d_in[7];
  const float* c1w  = (const float*)d_in[8];
  const float* c1b  = (const float*)d_in[9];
  const float* c2w  = (const float*)d_in[10];
  const float* c2b  = (const float*)d_in[11];
  const float* w1   = (const float*)d_in[12];
  const float* b1   = (const float*)d_in[13];
  const float* w2   = (const float*)d_in[14];
  const float* b2   = (const float*)d_in[15];
  const float* wrp  = (const float*)d_in[16];
  const float* br   = (const float*)d_in[17];
  float* out = (float*)d_out;
  char* ws = (char*)d_ws;
  (void)in_sizes; (void)n_in; (void)out_size; (void)ws_size;

  const size_t S_xtp = (size_t)16 * 514 * 512 * 2;  // 8,421,376 B padded transposed activations
  u16* xtp0  = (u16*)(ws);
  u16* xtp1  = (u16*)(ws + S_xtp);
  u16* xt2   = (u16*)(ws);            // overlays xtp0 (dead after conv1)
  u16* maxed = (u16*)(ws + S_xtp);    // overlays xtp1 (dead after conv2)
  u16* h2    = (u16*)(ws);            // overlays xt2+maxed (dead after gemm1)
  u16* h1    = (u16*)(ws + 2 * S_xtp);                            // 16 MiB
  u16* wg1   = (u16*)(ws + 2 * S_xtp + (size_t)16 * 1024 * 1024);
  u16* wg2   = wg1 + (size_t)512 * 1536;
  u16* w1b   = wg2 + (size_t)512 * 1536;
  u16* w2b   = w1b + (size_t)1024 * 512;
  u16* wrb   = w2b + (size_t)1024 * 1024;   // total ws use ~38.1 MiB

  k_transpose<<<dim3(16, 16, 16), 256, 0, stream>>>(x, xtp0);
  k_prep<<<2048, 256, 0, stream>>>(c1w, c2w, wg1, wg2, w1, w2, wrp, w1b,
                                   xtp0, xtp1, trig, labels, out);

  // conv1: y[b][t][o] = relu(sum_k xT0[b][t+w][i]*Wg1[o][k]) + xT0[b][t+1][o]
  // 128x64 tile, XCD-swizzled 1-D grid: each XCD owns 8 (y,z)-panels x 8 n-tiles;
  // per-XCD L2 footprint = 8*133KB (A) + 1.5MB (B) ~ 2.6MB < 4MB.
  k_gemm<128, 64, 2, 2, 1, 1, 1, 0, 0, 1><<<512, 256, 0, stream>>>(
      xtp0, 512, (long long)514 * 512, wg1, 1536, 0, 1536, c1b,
      xtp0 + 512, (long long)514 * 512,
      xtp1 + 512, (long long)514 * 512, 512, 8, 4, 8);
  // conv2 -> xt2 (B,T,E), unpadded
  k_gemm<128, 64, 2, 2, 1, 1, 1, 0, 0, 1><<<512, 256, 0, stream>>>(
      xtp1, 512, (long long)514 * 512, wg2, 1536, 0, 1536, c2b,
      xtp1 + 512, (long long)514 * 512,
      xt2, (long long)512 * 512, 512, 8, 4, 8);

  k_spanmax<<<8192, 256, 0, stream>>>(xt2, bidx, hidx, hspan, tidx, tspan, maxed);

  // h1 = relu(maxed @ w1^T + b1)   (8192x1024, K=512) — 128x64, 1024 blocks, swizzled:
  // per-XCD: 8 y-panels x 16 n-tiles; A 1MB + B 1MB resident.
  k_gemm<128, 64, 2, 2, 0, 1, 0, 0, 0, 1><<<1024, 256, 0, stream>>>(
      maxed, 512, 0, w1b, 512, 0, 512, b1, nullptr, 0, h1, 0, 1024, 16, 64, 8);
  // h2 = relu(h1 @ w2^T + b2)      (8192x1024, K=1024) — 128x128, 512 blocks, swizzled:
  // per-XCD: 8 y-panels x 8 n-tiles; A 2MB + B 2MB resident.
  k_gemm<128, 128, 2, 2, 0, 1, 0, 0, 0, 1><<<512, 256, 0, stream>>>(
      h1, 1024, 0, w2b, 1024, 0, 1024, b2, nullptr, 0, h2, 0, 1024, 8, 64, 8);
  // logits = h2 @ wr^T + br -> d_out[0 : 8192*32] f32; split-K x4 with atomic adds
  k_gemm<64, 32, 2, 2, 0, 0, 0, 1, 1, 0><<<dim3(1, 128, 4), 256, 0, stream>>>(
      h2, 1024, 256, wrb, 1024, 256, 256, br, nullptr, 0, out, 0, 32, 0, 0, 0);
}

// Round 10
// 225.045 us; speedup vs baseline: 1.1990x; 1.0983x over previous
//
#include <hip/hip_runtime.h>

typedef unsigned short u16;
typedef unsigned int u32;
typedef __attribute__((ext_vector_type(4))) float f32x4;
typedef __attribute__((ext_vector_type(8))) __bf16 bf16x8;
typedef __attribute__((ext_vector_type(4))) u16 u16x4;
typedef const __attribute__((address_space(1))) void* as1cv;
typedef __attribute__((address_space(3))) void* as3v;

static __device__ __forceinline__ float bf2f(u16 v) {
  union { u32 u; float f; } x; x.u = ((u32)v) << 16; return x.f;
}
static __device__ __forceinline__ u16 f2bf(float f) {
  union { float f; u32 u; } x; x.f = f;
  u32 r = x.u + 0x7FFFu + ((x.u >> 16) & 1u);
  return (u16)(r >> 16);
}

// ---------------- prep kernels ----------------

// x (B,E,T) f32 -> xtp (B, T+2, E) bf16, xtp[b][t+1][e] = x[b][e][t]; pad rows in k_prep
__global__ void __launch_bounds__(256) k_transpose(const float* __restrict__ x,
                                                   u16* __restrict__ xtp) {
  __shared__ float tile[32][33];
  const int b = blockIdx.z;
  const int t0 = blockIdx.x * 32, e0 = blockIdx.y * 32;
  const int tx = threadIdx.x & 31, ty = threadIdx.x >> 5;
  const float* src = x + (size_t)b * 512 * 512;
#pragma unroll
  for (int i = 0; i < 32; i += 8)
    tile[ty + i][tx] = src[(size_t)(e0 + ty + i) * 512 + t0 + tx];
  __syncthreads();
  u16* dst = xtp + (size_t)b * 514 * 512;
#pragma unroll
  for (int i = 0; i < 32; i += 8)
    dst[(size_t)(t0 + ty + i + 1) * 512 + e0 + tx] = f2bf(tile[tx][ty + i]);
}

// fused prep: conv-weight pack (idx<524288), MLP weight cvt (i<401408),
// logits zero + pad rows + passthrough (i<262144). grid 2048x256.
__global__ void __launch_bounds__(256) k_prep(
    const float* __restrict__ wa, const float* __restrict__ wb,
    u16* __restrict__ ga, u16* __restrict__ gb,
    const float* __restrict__ w1, const float* __restrict__ w2,
    const float* __restrict__ wr, u16* __restrict__ wdst,
    u16* __restrict__ xtp0, u16* __restrict__ xtp1,
    const float* __restrict__ trig, const int* __restrict__ labels,
    float* __restrict__ out) {
  const int idx = blockIdx.x * 256 + threadIdx.x;  // < 524288
  {  // conv weights (E,E,W) f32 -> Wg (E, 3*E) bf16, Wg[o][w*512+i] = w[o][i][w]
    const float* w = (idx < 262144) ? wa : wb;
    u16* g = (idx < 262144) ? ga : gb;
    const int id = idx & 262143;
    const int o = id >> 9, i = id & 511;
    const float* p = w + (size_t)id * 3;
    g[(size_t)o * 1536 + i]        = f2bf(p[0]);
    g[(size_t)o * 1536 + 512 + i]  = f2bf(p[1]);
    g[(size_t)o * 1536 + 1024 + i] = f2bf(p[2]);
  }
  if (idx < 401408) {  // w1|w2|wr f32 -> contiguous bf16, x4 elems
    const int e0 = idx * 4;
    const float* src; int off;
    if (e0 < 524288)       { src = w1; off = e0; }
    else if (e0 < 1572864) { src = w2; off = e0 - 524288; }
    else                   { src = wr; off = e0 - 1572864; }
    const float4 v = *(const float4*)(src + off);
    u16x4 r; r.x = f2bf(v.x); r.y = f2bf(v.y); r.z = f2bf(v.z); r.w = f2bf(v.w);
    *(u16x4*)(wdst + e0) = r;
  }
  if (idx < 262144) out[idx] = 0.f;  // logits zero-init (split-K atomics)
  if (idx < 16384) {                 // zero pad rows of xtp0/xtp1
    const int b = idx >> 10, rem = idx & 1023;
    const int row = (rem >> 9) ? 513 : 0, e = rem & 511;
    const size_t off = (size_t)b * 514 * 512 + (size_t)row * 512 + e;
    xtp0[off] = 0;
    xtp1[off] = 0;
  }
  if (idx < 8192) {
    out[262144 + idx] = trig[idx];           // trig_attn passthrough (B*T)
    out[270336 + idx] = (float)labels[idx];  // rel_labels passthrough (P)
  }
}

// ---------------- span max ----------------
__global__ void __launch_bounds__(256) k_spanmax(const u16* __restrict__ xt2,
    const int* __restrict__ bidx, const int* __restrict__ hidx, const int* __restrict__ hspan,
    const int* __restrict__ tidx, const int* __restrict__ tspan, u16* __restrict__ maxed) {
  const int p = blockIdx.x;
  const int b = bidx[p], h0 = hidx[p], hn = hspan[p], t0 = tidx[p], tn = tspan[p];
  const u32* base = (const u32*)(xt2 + (size_t)b * 512 * 512);
  const int e = threadIdx.x;  // covers bf16 pair (2e, 2e+1)
  float m0 = -1e30f, m1 = -1e30f, q0 = -1e30f, q1 = -1e30f;
  for (int s = 0; s < hn; ++s) {
    const u32 v = base[(size_t)(h0 + s) * 256 + e];
    m0 = fmaxf(m0, bf2f((u16)v));
    m1 = fmaxf(m1, bf2f((u16)(v >> 16)));
  }
  for (int s = 0; s < tn; ++s) {
    const u32 v = base[(size_t)(t0 + s) * 256 + e];
    q0 = fmaxf(q0, bf2f((u16)v));
    q1 = fmaxf(q1, bf2f((u16)(v >> 16)));
  }
  const u32 r = (u32)f2bf(m0 + q0) | ((u32)f2bf(m1 + q1) << 16);
  ((u32*)(maxed + (size_t)p * 512))[e] = r;
}

// ---------------- conv (tap-accumulate, K=512, NT=16 — was im2col K=1536/NT=48) ----------------
// out[b][t][o] = relu(sum_w sum_i xtp[b][t+w][i] * Wg[o][w*512+i]) + bias[o] + xtp[b][t+1][o]
// A-tile staged ONCE covering the 3-tap halo (rows m0..m0+143); per K-step 3 MFMA groups
// read LDS rows +0/+1/+2. Barriers 48->16, A global traffic /3, same MFMA/ds_read totals.
// BM=128, BN=64, 4 waves (2x2), FM=4, FN=2. Grid 512, XCD-swizzled like r8.
__global__ void __launch_bounds__(256, 2) k_conv(
    const u16* __restrict__ Abase,   // xtp (B,514,512) padded
    const u16* __restrict__ Bw,      // Wg (512,1536)
    const float* __restrict__ bias,
    u16* __restrict__ outbase,       // row stride 512
    long long batchA, long long batchO) {
  constexpr int ASZ = 144 * 32;
  __shared__ __align__(16) u16 lds[2][ASZ + 192 * 32];  // 42 KB total
  const int tid = threadIdx.x, wave = tid >> 6, lane = tid & 63;
  const int lin = blockIdx.x;
  const int xcd = lin & 7, slot = lin >> 3;
  const int n0 = (slot & 7) * 64;
  const int p = xcd * 8 + (slot >> 3);
  const int m0 = (p & 3) * 128;
  const int z = p >> 2;
  const u16* Ab = Abase + (size_t)z * batchA;
  u16* outp = outbase + (size_t)z * batchO;

  auto stage = [&](int t, int buf) {
    const int k0 = t << 5;
    for (int c = wave; c < 21; c += 4) {
      const u16* gsrc; u16* ldst;
      if (c < 9) {  // A: 9 chunks x 16 rows (rows m0..m0+143; used <= m0+129, overrun reads unused)
        ldst = &lds[buf][c * 512];
        const int row = m0 + c * 16 + (lane >> 2);
        gsrc = Ab + (size_t)row * 512 + k0 + ((lane & 3) << 3);
      } else {      // B: 3 taps x 4 chunks x 16 rows
        const int cb = c - 9, w = cb >> 2, r0 = (cb & 3) << 4;
        ldst = &lds[buf][ASZ + (w * 64 + r0) * 32];
        const int row = n0 + r0 + (lane >> 2);
        gsrc = Bw + (size_t)row * 1536 + (w << 9) + k0 + ((lane & 3) << 3);
      }
      __builtin_amdgcn_global_load_lds((as1cv)gsrc, (as3v)ldst, 16, 0, 0);
    }
  };

  f32x4 acc[4][2];
  const f32x4 zero4 = {0.f, 0.f, 0.f, 0.f};
#pragma unroll
  for (int m = 0; m < 4; ++m)
#pragma unroll
    for (int n = 0; n < 2; ++n) acc[m][n] = zero4;

  const int wrow = wave >> 1, wcol = wave & 1;
  const int rsel = lane & 15, kc = (lane >> 4) << 3;

  stage(0, 0);
  __syncthreads();
  int cur = 0;
  for (int t = 0; t < 16; ++t) {
    if (t + 1 < 16) stage(t + 1, cur ^ 1);
    const u16* As = lds[cur];
    const u16* Bs = lds[cur] + ASZ;
#pragma unroll
    for (int w = 0; w < 3; ++w) {
      bf16x8 af[4], bq[2];
#pragma unroll
      for (int m = 0; m < 4; ++m)
        af[m] = *(const bf16x8*)&As[(wrow * 64 + m * 16 + rsel + w) * 32 + kc];
#pragma unroll
      for (int n = 0; n < 2; ++n)
        bq[n] = *(const bf16x8*)&Bs[(w * 64 + wcol * 32 + n * 16 + rsel) * 32 + kc];
#pragma unroll
      for (int m = 0; m < 4; ++m)
#pragma unroll
        for (int n = 0; n < 2; ++n)
          acc[m][n] = __builtin_amdgcn_mfma_f32_16x16x32_bf16(af[m], bq[n], acc[m][n], 0, 0, 0);
    }
    __syncthreads();
    cur ^= 1;
  }

  const int rowbase = m0 + wrow * 64 + ((lane >> 4) << 2);
  const int colbase = n0 + wcol * 32 + rsel;
  const float bv0 = bias[colbase], bv1 = bias[colbase + 16];
  const u16* Rb = Ab + 512;  // residual: xtp row t+1, same channel
#pragma unroll
  for (int m = 0; m < 4; ++m) {
#pragma unroll
    for (int r = 0; r < 4; ++r) {
      const int row = rowbase + m * 16 + r;
#pragma unroll
      for (int n = 0; n < 2; ++n) {
        const int col = colbase + n * 16;
        float v = fmaxf(acc[m][n][r] + (n ? bv1 : bv0), 0.f);
        v += bf2f(Rb[(size_t)row * 512 + col]);
        outp[(size_t)row * 512 + col] = f2bf(v);
      }
    }
  }
}

// ---------------- GEMM (2-phase, global_load_lds, 16x16x32 bf16 MFMA, param K-step) ----------------
// C[m][n] = sum_k A[m][k]*Bw[n][k]; epilogue: +bias[n], opt relu, bf16/f32 store,
// opt atomicAdd (split-K; bias at z==0 only). KS = K-step (32 or 64; KS=64 halves barriers).
// SWZ: 1-D grid, lin%8 = XCD owns whole (y,z)-panels with all n-tiles (L2 residency).
template<int BM, int BN, int WM, int WN, int KS, int RELU, int OUTF32, int ATOMIC, int SWZ>
__global__ void __launch_bounds__(256, 2) k_gemm(
    const u16* __restrict__ A, int strideA, long long batchA,
    const u16* __restrict__ Bw, int strideB, long long batchB, int K,
    const float* __restrict__ bias,
    void* __restrict__ outp, long long batchO, int strideO,
    int swz_nx, int swz_nyb, int swz_pp) {
  constexpr int FM = BM / (16 * WM);
  constexpr int FN = BN / (16 * WN);
  constexpr int LPR = KS / 8;               // lanes per staged row
  constexpr int RPC = 64 / LPR;             // rows per 1KB stage chunk
  constexpr int NCH = (BM + BN) / RPC;      // chunks per K-step
  __shared__ __align__(16) u16 lds[2][(BM + BN) * KS];
  const int tid = threadIdx.x;
  const int wave = tid >> 6, lane = tid & 63;
  int m0, n0, z;
  if constexpr (SWZ) {
    const int lin = blockIdx.x;
    const int xcd = lin & 7, slot = lin >> 3;
    const int xb = slot % swz_nx;
    const int p  = xcd * swz_pp + slot / swz_nx;
    m0 = (p % swz_nyb) * BM;
    n0 = xb * BN;
    z  = p / swz_nyb;
  } else {
    m0 = blockIdx.y * BM; n0 = blockIdx.x * BN; z = blockIdx.z;
  }
  const u16* Ab = A + (size_t)z * batchA;
  const u16* Bb = Bw + (size_t)z * batchB;
  const int NT = K / KS;

  auto stage = [&](int t, int buf) {
    const int k0 = t * KS;
    const int lrow = lane / LPR, lcol = (lane % LPR) << 3;
    for (int c = wave; c < NCH; c += 4) {
      const int gr = c * RPC + lrow;
      const bool isA = gr < BM;
      const int row = isA ? (m0 + gr) : (n0 + gr - BM);
      const u16* gsrc = (isA ? Ab + (size_t)row * strideA : Bb + (size_t)row * strideB)
                        + k0 + lcol;
      __builtin_amdgcn_global_load_lds((as1cv)gsrc, (as3v)&lds[buf][c * 512], 16, 0, 0);
    }
  };

  f32x4 acc[FM][FN];
  const f32x4 zero4 = {0.f, 0.f, 0.f, 0.f};
#pragma unroll
  for (int m = 0; m < FM; ++m)
#pragma unroll
    for (int n = 0; n < FN; ++n) acc[m][n] = zero4;

  const int wrow = wave / WN, wcol = wave % WN;
  const int rsel = lane & 15;
  const int kc = (lane >> 4) << 3;

  stage(0, 0);
  __syncthreads();
  int cur = 0;
  for (int t = 0; t < NT; ++t) {
    if (t + 1 < NT) stage(t + 1, cur ^ 1);
    const u16* As = lds[cur];
    const u16* Bs = lds[cur] + BM * KS;
#pragma unroll
    for (int ks = 0; ks < KS / 32; ++ks) {
      bf16x8 af[FM], bq[FN];
#pragma unroll
      for (int m = 0; m < FM; ++m)
        af[m] = *(const bf16x8*)&As[(wrow * FM * 16 + m * 16 + rsel) * KS + ks * 32 + kc];
#pragma unroll
      for (int n = 0; n < FN; ++n)
        bq[n] = *(const bf16x8*)&Bs[(wcol * FN * 16 + n * 16 + rsel) * KS + ks * 32 + kc];
#pragma unroll
      for (int m = 0; m < FM; ++m)
#pragma unroll
        for (int n = 0; n < FN; ++n)
          acc[m][n] = __builtin_amdgcn_mfma_f32_16x16x32_bf16(af[m], bq[n], acc[m][n], 0, 0, 0);
    }
    __syncthreads();
    cur ^= 1;
  }

  // epilogue: C/D layout col = lane&15, row = (lane>>4)*4 + reg  [verified m89/m91]
  const int rowbase = m0 + wrow * FM * 16 + ((lane >> 4) << 2);
  const int colbase = n0 + wcol * FN * 16 + rsel;
  float bv[FN];
#pragma unroll
  for (int n = 0; n < FN; ++n)
    bv[n] = (!ATOMIC || z == 0) ? bias[colbase + n * 16] : 0.f;
  float* of = (float*)outp;
  u16* ob = (u16*)outp;
  const size_t obase = (size_t)z * batchO;
#pragma unroll
  for (int m = 0; m < FM; ++m) {
#pragma unroll
    for (int r = 0; r < 4; ++r) {
      const int row = rowbase + m * 16 + r;
#pragma unroll
      for (int n = 0; n < FN; ++n) {
        const int col = colbase + n * 16;
        float v = acc[m][n][r] + bv[n];
        if (RELU) v = fmaxf(v, 0.f);
        const size_t o = obase + (size_t)row * strideO + col;
        if (ATOMIC) atomicAdd(&of[o], v);
        else if (OUTF32) of[o] = v;
        else ob[o] = f2bf(v);
      }
    }
  }
}

// ---------------- launcher ----------------
extern "C" void kernel_launch(void* const* d_in, const int* in_sizes, int n_in,
                              void* d_out, int out_size, void* d_ws, size_t ws_size,
                              hipStream_t stream) {
  const float* x    = (const float*)d_in[0];
  const float* trig = (const float*)d_in[1];
  const int* bidx   = (const int*)d_in[2];
  const int* hidx   = (const int*)d_in[3];
  const int* hspan  = (const int*)d_in[4];
  const int* tidx   = (const int*)d_in[5];
  const int* tspan  = (const int*)d_in[6];
  const int* labels = (const int*)d_in[7];
  const float* c1w  = (const float*)d_in[8];
  const float* c1b  = (const float*)d_in[9];
  const float* c2w  = (const float*)d_in[10];
  const float* c2b  = (const float*)d_in[11];
  const float* w1   = (const float*)d_in[12];
  const float* b1   = (const float*)d_in[13];
  const float* w2   = (const float*)d_in[14];
  const float* b2   = (const float*)d_in[15];
  const float* wrp  = (const float*)d_in[16];
  const float* br   = (const float*)d_in[17];
  float* out = (float*)d_out;
  char* ws = (char*)d_ws;
  (void)in_sizes; (void)n_in; (void)out_size; (void)ws_size;

  const size_t S_xtp = (size_t)16 * 514 * 512 * 2;  // 8,421,376 B padded transposed activations
  u16* xtp0  = (u16*)(ws);
  u16* xtp1  = (u16*)(ws + S_xtp);
  u16* xt2   = (u16*)(ws);            // overlays xtp0 (dead after conv1)
  u16* maxed = (u16*)(ws + S_xtp);    // overlays xtp1 (dead after conv2)
  u16* h2    = (u16*)(ws);            // overlays xt2+maxed (dead after gemm1)
  u16* h1    = (u16*)(ws + 2 * S_xtp);                            // 16 MiB
  u16* wg1   = (u16*)(ws + 2 * S_xtp + (size_t)16 * 1024 * 1024);
  u16* wg2   = wg1 + (size_t)512 * 1536;
  u16* w1b   = wg2 + (size_t)512 * 1536;
  u16* w2b   = w1b + (size_t)1024 * 512;
  u16* wrb   = w2b + (size_t)1024 * 1024;   // total ws use ~38.1 MiB

  k_transpose<<<dim3(16, 16, 16), 256, 0, stream>>>(x, xtp0);
  k_prep<<<2048, 256, 0, stream>>>(c1w, c2w, wg1, wg2, w1, w2, wrp, w1b,
                                   xtp0, xtp1, trig, labels, out);

  // conv1 -> xtp1 (padded rows, +512 = row t+1); conv2 -> xt2 (unpadded)
  k_conv<<<512, 256, 0, stream>>>(xtp0, wg1, c1b, xtp1 + 512,
                                  (long long)514 * 512, (long long)514 * 512);
  k_conv<<<512, 256, 0, stream>>>(xtp1, wg2, c2b, xt2,
                                  (long long)514 * 512, (long long)512 * 512);

  k_spanmax<<<8192, 256, 0, stream>>>(xt2, bidx, hidx, hspan, tidx, tspan, maxed);

  // h1 = relu(maxed @ w1^T + b1)   (8192x1024, K=512) — 128x64, KS=32, 1024 blocks (control arm)
  k_gemm<128, 64, 2, 2, 32, 1, 0, 0, 1><<<1024, 256, 0, stream>>>(
      maxed, 512, 0, w1b, 512, 0, 512, b1, h1, 0, 1024, 16, 64, 8);
  // h2 = relu(h1 @ w2^T + b2)      (8192x1024, K=1024) — 128x128, KS=64 (barriers 32->16)
  k_gemm<128, 128, 2, 2, 64, 1, 0, 0, 1><<<512, 256, 0, stream>>>(
      h1, 1024, 0, w2b, 1024, 0, 1024, b2, h2, 0, 1024, 8, 64, 8);
  // logits = h2 @ wr^T + br -> d_out f32; split-K x4 with atomic adds
  k_gemm<64, 32, 2, 2, 32, 0, 1, 1, 0><<<dim3(1, 128, 4), 256, 0, stream>>>(
      h2, 1024, 256, wrb, 1024, 256, 256, br, out, 0, 32, 0, 0, 0);
}